// Round 9
// baseline (248.681 us; speedup 1.0000x reference)
//
#include <hip/hip_runtime.h>

// QuadraticBaseMorpho: out[h][w] = max_{dy,dx in [-3,3]} xpad[h+dy][w+dx] + nb[dy+3][dx+3]
// xpad = x padded with -10000. nb = -(se/se.max()) with center forced to -10000.
// se is even-symmetric -> the [::-1,::-1] flip is identity.
// Input (8,64,256,256) fp32 = 512 planes of 256x256.
//
// Round-9: the last ablation cell. Evidence so far: kernel time is pinned at
// ~93 us = 225 MB / 2.4 TB/s in EVERY structure (r0-r8); VALU halving (r1),
// occupancy 35-70% (r8/r3), LDS removal (r3), prefetch attempts (r4-r8) all
// null; r1's throttled profile shows dur tracks memory rate with core idle.
// Untested: high TLP + minimal requests + minimal amplification at once.
// This kernel: 8 contiguous output rows per wave (4096 blocks, ~24-32
// waves/CU), ONE 1-KiB load per input row (halo quads come from neighbor
// lanes via 6 __shfl ops instead of 2 extra overlapping loads: vmem requests
// halved, L1 halo traffic gone, DS pipe was idle). No pins, no fences, no
// register ring - scheduling is left entirely to the compiler; latency
// hiding comes from wave count. Compute body = validated r2/r8 packed form.
// If this is null too, the 2.4 TB/s mixed-stream rate is the roofline.
//
// Per (t,c,dd): 3 v_pk_add_f32 + 1 add + 3 v_max3 + 1 max. Pad rows skipped
// (-MAXV+w can never beat a real candidate; dy=0 always real).

#define MAXV 10000.0f

constexpr int H = 256;
constexpr int W = 256;

typedef float vf4 __attribute__((ext_vector_type(4)));
typedef float vf2 __attribute__((ext_vector_type(2)));

__global__ __launch_bounds__(256, 6) void morpho_kernel(
    const float* __restrict__ x,
    const float* __restrict__ k1p,
    const float* __restrict__ k2p,
    const float* __restrict__ k3p,
    float* __restrict__ out) {
  const int tid = threadIdx.x;
  const int lane = tid & 63;
  const int wid = __builtin_amdgcn_readfirstlane(tid >> 6);  // wave id, uniform
  const int p = blockIdx.x >> 3;                 // plane (512)
  const int y0w = ((blockIdx.x & 7) * 4 + wid) * 8;  // wave's first output row

  const float* __restrict__ xp = x + (size_t)p * (H * W);
  float* __restrict__ op = out + (size_t)p * (H * W);

  // ---- SE: one weight per lane (8x8 grid), shuffle-max, readlane -> SGPRs ----
  const float k1v = k1p[0], k2v = k2p[0], k3v = k3p[0];
  const int ia = lane >> 3, ib = lane & 7;
  const float xg = (float)(((ib < 6) ? ib : 6) - 3);   // clamp dup lanes; max unaffected
  const float yg = (float)(((ia < 6) ? ia : 6) - 3);
  const float sev = k1v * (xg * xg) + 2.0f * k2v * (xg * yg) + k3v * (yg * yg);
  float mx = sev;
#pragma unroll
  for (int off = 32; off; off >>= 1) mx = fmaxf(mx, __shfl_xor(mx, off, 64));
  const float wv = 0.0f - sev * (1.0f / mx);

  // weight row d: pairs (w0,w1)(w2,w3)(w4,w5) + scalar w6 -> 49 SGPRs total
  vf2 wp[7][3];
  float w6[7];
#pragma unroll
  for (int d = 0; d < 7; ++d) {
#pragma unroll
    for (int m = 0; m < 3; ++m) {
      vf2 pr;
      pr.x = __int_as_float(__builtin_amdgcn_readlane(__float_as_int(wv), d * 8 + 2 * m));
      pr.y = __int_as_float(__builtin_amdgcn_readlane(__float_as_int(wv), d * 8 + 2 * m + 1));
      wp[d][m] = pr;
    }
    w6[d] = __int_as_float(__builtin_amdgcn_readlane(__float_as_int(wv), d * 8 + 6));
  }
  wp[3][1].y = -MAXV;                            // masked center (d=3, j=3)

  const bool l0 = (lane == 0);
  const bool l63 = (lane == 63);
  const int o1 = lane * 4;                       // own quad: cols lane*4 .. +3

  // ---- 7 rotating accumulator slots (slot = t % 7; t=0 and t=7 share 0,
  //      live ranges disjoint: t=0 retires at iy=6, t=7 starts at iy=7) ----
  float acc[7][4];
#pragma unroll
  for (int s = 0; s < 7; ++s)
#pragma unroll
    for (int c = 0; c < 4; ++c) acc[s][c] = -INFINITY;

#pragma unroll
  for (int iy = 0; iy < 14; ++iy) {              // input rows y0w-3 .. y0w+10
    const int r = y0w - 3 + iy;
    const int rc = (r < 0) ? 0 : ((r > H - 1) ? H - 1 : r);   // clamp (branchless)
    const vf4 q1 = *reinterpret_cast<const vf4*>(xp + rc * W + o1);

    // pad rows possible only at compile-time edge iys -> interior branch-free
    if ((iy >= 3 && iy <= 10) || (r >= 0 && r < H)) {
      // halo quads from neighbor lanes (whole wave holds one row):
      // q0 = lane-1's q1 (cols lane*4-4..-1), q2 = lane+1's q1 (cols +4..+7)
      vf4 q0, q2;
      q0.x = q1.x;                               // buf[0] unused
      q0.y = __shfl_up(q1.y, 1, 64);
      q0.z = __shfl_up(q1.z, 1, 64);
      q0.w = __shfl_up(q1.w, 1, 64);
      q2.x = __shfl_down(q1.x, 1, 64);
      q2.y = __shfl_down(q1.y, 1, 64);
      q2.z = __shfl_down(q1.z, 1, 64);
      q2.w = q1.w;                               // buf[11] unused

      // edge fixes: lane 0's cols -3..-1, lane 63's cols 256..258 -> -MAXV
      q0.y = l0 ? -MAXV : q0.y;
      q0.z = l0 ? -MAXV : q0.z;
      q0.w = l0 ? -MAXV : q0.w;
      q2.x = l63 ? -MAXV : q2.x;
      q2.y = l63 ? -MAXV : q2.y;
      q2.z = l63 ? -MAXV : q2.z;

      // odd-start pairs: (b1,b2)(b3,b4)(b5,b6)(b7,b8)
      const vf2 O0 = __builtin_shufflevector(q0, q0, 1, 2);
      const vf2 O1 = __builtin_shufflevector(q0, q1, 3, 4);
      const vf2 O2 = __builtin_shufflevector(q1, q1, 1, 2);
      const vf2 O3 = __builtin_shufflevector(q1, q2, 3, 4);
      // even-start pairs (free quad sub-pairs): (b2,b3)(b4,b5)(b6,b7)(b8,b9)
      const vf2 E0 = __builtin_shufflevector(q0, q0, 2, 3);
      const vf2 E1 = __builtin_shufflevector(q1, q1, 0, 1);
      const vf2 E2 = __builtin_shufflevector(q1, q1, 2, 3);
      const vf2 E3 = __builtin_shufflevector(q2, q2, 0, 1);

      const vf2 P[4][3] = {{O0, O1, O2}, {E0, E1, E2}, {O1, O2, O3}, {E1, E2, E3}};
      const float T[4] = {q1.w, q2.x, q2.y, q2.z};

      // contribute to all live outputs t = iy-dd, dd = weight row (dy+3)
#pragma unroll
      for (int dd = 0; dd < 7; ++dd) {
        const int t = iy - dd;
        if (t < 0 || t > 7) continue;            // compile-time dead
        const int st = t % 7;                    // compile-time
#pragma unroll
        for (int c = 0; c < 4; ++c) {
          const vf2 a = P[c][0] + wp[dd][0];     // v_pk_add_f32
          const vf2 b = P[c][1] + wp[dd][1];     // v_pk_add_f32
          const vf2 g = P[c][2] + wp[dd][2];     // v_pk_add_f32
          const float s6 = T[c] + w6[dd];
          const float m0 = fmaxf(fmaxf(a.x, a.y), b.x);   // v_max3
          const float m1 = fmaxf(fmaxf(b.y, g.x), g.y);   // v_max3
          const float m2 = fmaxf(fmaxf(s6, m0), m1);      // v_max3
          acc[st][c] = fmaxf(acc[st][c], m2);
        }
      }
    }

    // ---- retire output row t = iy-6 (slot (iy-6)%7) ----
    if (iy >= 6) {                               // compile-time
      const int tr = iy - 6;
      const int st = tr % 7;                     // compile-time
      vf4 v;
      v.x = acc[st][0];
      v.y = acc[st][1];
      v.z = acc[st][2];
      v.w = acc[st][3];
      __builtin_nontemporal_store(
          v, reinterpret_cast<vf4*>(&op[(y0w + tr) * W + o1]));
      if (iy == 6) {                             // slot 0 reused by t = 7
#pragma unroll
        for (int c = 0; c < 4; ++c) acc[st][c] = -INFINITY;
      }
    }
  }
}

extern "C" void kernel_launch(void* const* d_in, const int* in_sizes, int n_in,
                              void* d_out, int out_size, void* d_ws, size_t ws_size,
                              hipStream_t stream) {
  const float* x = (const float*)d_in[0];
  const float* k1 = (const float*)d_in[1];
  const float* k2 = (const float*)d_in[2];
  const float* k3 = (const float*)d_in[3];
  float* outp = (float*)d_out;

  const int planes = 8 * 64;                     // 512
  const int blocks = planes * 8;                 // 4096 (4 waves x 8 rows)
  morpho_kernel<<<dim3(blocks), dim3(256), 0, stream>>>(x, k1, k2, k3, outp);
}